// Round 14
// baseline (324.258 us; speedup 1.0000x reference)
//
#include <hip/hip_runtime.h>
#include <hip/hip_bf16.h>

// DigitCaps, fp32 in / fp32 out:
//   u [16,1152,8], W [10,1152,16,8], Bp [10,1,1152], out [16,10,16]
// Exact algebra: A_sum[b,d,m] = dot(T[b,d,:], U_hat[b,d,m,:])/sqrt8,
//   T = sum_n U_hat;  C = softmax_d;  S = sum_n (Bp+C)*U_hat;  squash(S).
// Round-13 lesson: dur is dispatch-structure-bound (83us ~= round 10's 84.8
// despite different kernels). Round 14: ONE kernel + software grid barriers
// (co-residency guaranteed: 576 blocks, 11.3KB LDS, ~100 VGPR -> >=2048
// capacity; cooperative API itself failed in r11 but plain launch + counter
// barrier needs only co-residency). W staged once; uh kept in registers so
// phase B does zero W/u traffic. Barriers: agent-scope atomics (cross-XCD
// coherence point); counters zeroed by a 16B memset each call.
constexpr int BN = 16, NN = 1152, DP = 8, ND = 10, DD = 16;
constexpr int NCH = 2;                   // n's per block
constexpr int NBLK = NN / NCH;           // 576 blocks
constexpr int CELLS = BN * ND * DD;      // 2560; cell = d*256 + b*16 + j
constexpr int RL = 16;                   // reduction lanes per cell
constexpr int RB = CELLS / RL;           // 160 reducer blocks
constexpr int WCH = NCH * ND;            // 20 staged W chunks

__device__ __forceinline__ void gridbar(unsigned* __restrict__ cnt) {
    __syncthreads();
    if (threadIdx.x == 0) {
        __threadfence();   // release: drain + flush dirty L2 to coherence pt
        __hip_atomic_fetch_add(cnt, 1u, __ATOMIC_ACQ_REL,
                               __HIP_MEMORY_SCOPE_AGENT);
        while (__hip_atomic_load(cnt, __ATOMIC_ACQUIRE,
                                 __HIP_MEMORY_SCOPE_AGENT) < (unsigned)NBLK)
            __builtin_amdgcn_s_sleep(1);
        __threadfence();   // acquire: invalidate stale lines
    }
    __syncthreads();
}

__global__ __launch_bounds__(256) void caps_fused(
    const float* __restrict__ u, const float* __restrict__ W,
    const float* __restrict__ Bp, float* __restrict__ Tp,
    float* __restrict__ T, float* __restrict__ Sp,
    float* __restrict__ out, unsigned* __restrict__ cnt)
{
    __shared__ float sbuf[CELLS + 256];  // Wl(10K)+ul(1K) -> red -> Tl(10K)
    const int blk = blockIdx.x, t = threadIdx.x, j = t & 15, b = t >> 4;
    const int n0 = blk * NCH;
    constexpr float RS8 = 0.35355339059327373f;  // 1/sqrt(8)

    // ---- stage W (640 float4, independent) + u (64 float4) ----
    float* Wl = sbuf;            // 2560 floats
    float* ul = sbuf + CELLS;    // 256 floats
    for (int g = t; g < WCH * 32; g += 256) {
        const int c = g >> 5, w = g & 31;
        const int nn = c / ND, d = c - nn * ND;
        reinterpret_cast<float4*>(Wl)[g] =
            *reinterpret_cast<const float4*>(
                W + ((size_t)d * NN + (n0 + nn)) * (DD * DP) + w * 4);
    }
    if (t < BN * NCH * 2) {
        const int bb = t >> 2, r = t & 3, nn = r >> 1, half = r & 1;
        reinterpret_cast<float4*>(ul)[t] =
            *reinterpret_cast<const float4*>(
                u + ((size_t)bb * NN + (n0 + nn)) * DP + half * 4);
    }
    __syncthreads();

    // ---- phase A: uh[nn][d] (kept in registers for phase B), partial T ----
    float uh[NCH][ND], Tacc[ND];
#pragma unroll
    for (int d = 0; d < ND; ++d) Tacc[d] = 0.f;
#pragma unroll
    for (int nn = 0; nn < NCH; ++nn) {
        const float4 u0 = reinterpret_cast<const float4*>(ul)[b * 4 + nn * 2];
        const float4 u1 = reinterpret_cast<const float4*>(ul)[b * 4 + nn * 2 + 1];
#pragma unroll
        for (int d = 0; d < ND; ++d) {
            const float4* wp =
                reinterpret_cast<const float4*>(Wl) + (nn * ND + d) * 32 + j * 2;
            const float4 w0 = wp[0], w1 = wp[1];
            const float s =
                  w0.x * u0.x + w0.y * u0.y + w0.z * u0.z + w0.w * u0.w
                + w1.x * u1.x + w1.y * u1.y + w1.z * u1.z + w1.w * u1.w;
            uh[nn][d] = s;
            Tacc[d] += s;
        }
    }
    {
        float* dst = Tp + (size_t)blk * CELLS;
#pragma unroll
        for (int d = 0; d < ND; ++d) dst[d * 256 + t] = Tacc[d];
    }
    gridbar(&cnt[0]);

    // ---- reduce Tp[576][2560] -> T[2560] on blocks 0..159 ----
    if (blk < RB) {
        const int cell = blk * RL + j, cc = t >> 4;
        float s0 = 0.f, s1 = 0.f, s2 = 0.f, s3 = 0.f;
        for (int k = 0; k < NBLK / RL; k += 4) {   // 36 = 9 x 4 independent
            s0 += Tp[(size_t)(cc + RL * (k + 0)) * CELLS + cell];
            s1 += Tp[(size_t)(cc + RL * (k + 1)) * CELLS + cell];
            s2 += Tp[(size_t)(cc + RL * (k + 2)) * CELLS + cell];
            s3 += Tp[(size_t)(cc + RL * (k + 3)) * CELLS + cell];
        }
        sbuf[t] = (s0 + s1) + (s2 + s3);           // reuse LDS as red[256]
        __syncthreads();
        if (t < RL) {
            float acc = 0.f;
#pragma unroll
            for (int g = 0; g < RL; ++g) acc += sbuf[t + RL * g];
            T[blk * RL + t] = acc;
        }
    }
    gridbar(&cnt[1]);

    // ---- stage T (overwrites Wl; safe after barrier's syncthreads) ----
    for (int g = t; g < CELLS / 4; g += 256)
        reinterpret_cast<float4*>(sbuf)[g] =
            reinterpret_cast<const float4*>(T)[g];
    __syncthreads();

    // ---- phase B: scores -> softmax_d -> partial S (zero W/u traffic) ----
    {
        float Treg[ND];
#pragma unroll
        for (int q = 0; q < ND; ++q) Treg[q] = sbuf[q * 256 + t];
        float Sacc[ND];
#pragma unroll
        for (int q = 0; q < ND; ++q) Sacc[q] = 0.f;
#pragma unroll
        for (int nn = 0; nn < NCH; ++nn) {
            const int n = n0 + nn;
            float a[ND];
#pragma unroll
            for (int q = 0; q < ND; ++q) {
                float v = Treg[q] * uh[nn][q];     // butterfly over 16 j-lanes
                v += __shfl_xor(v, 8, 16);
                v += __shfl_xor(v, 4, 16);
                v += __shfl_xor(v, 2, 16);
                v += __shfl_xor(v, 1, 16);
                a[q] = v * RS8;
            }
            float m = a[0];
#pragma unroll
            for (int q = 1; q < ND; ++q) m = fmaxf(m, a[q]);
            float e[ND], se = 0.f;
#pragma unroll
            for (int q = 0; q < ND; ++q) { e[q] = expf(a[q] - m); se += e[q]; }
            const float inv_se = 1.f / se;
#pragma unroll
            for (int q = 0; q < ND; ++q)
                Sacc[q] += (Bp[q * NN + n] + e[q] * inv_se) * uh[nn][q];
        }
        float* dst = Sp + (size_t)blk * CELLS;
#pragma unroll
        for (int q = 0; q < ND; ++q) dst[q * 256 + t] = Sacc[q];
    }
    gridbar(&cnt[2]);

    // ---- reduce Sp + fused squash on blocks 0..159 = (q,b) ----
    if (blk < RB) {
        const int q = blk >> 4, bb = blk & 15, cc = t >> 4;
        const int cell = q * 256 + bb * 16 + j;
        float s0 = 0.f, s1 = 0.f, s2 = 0.f, s3 = 0.f;
        for (int k = 0; k < NBLK / RL; k += 4) {
            s0 += Sp[(size_t)(cc + RL * (k + 0)) * CELLS + cell];
            s1 += Sp[(size_t)(cc + RL * (k + 1)) * CELLS + cell];
            s2 += Sp[(size_t)(cc + RL * (k + 2)) * CELLS + cell];
            s3 += Sp[(size_t)(cc + RL * (k + 3)) * CELLS + cell];
        }
        __syncthreads();                           // sbuf reuse (vs Tl reads)
        sbuf[t] = (s0 + s1) + (s2 + s3);
        __syncthreads();
        if (t < RL) {                              // t = j
            float Sv = 0.f;
#pragma unroll
            for (int g = 0; g < RL; ++g) Sv += sbuf[t + RL * g];
            float n2 = Sv * Sv;
#pragma unroll
            for (int off = 8; off >= 1; off >>= 1)
                n2 += __shfl_xor(n2, off, 16);
            const float nrm = sqrtf(n2);
            const float coef = 1.f - 1.f / (expf(nrm) + 1e-7f);
            out[((size_t)bb * ND + q) * DD + t] = Sv * (coef / (nrm + 1e-7f));
        }
    }
}

extern "C" void kernel_launch(void* const* d_in, const int* in_sizes, int n_in,
                              void* d_out, int out_size, void* d_ws, size_t ws_size,
                              hipStream_t stream) {
    const float* u  = nullptr;   // 147456
    const float* W  = nullptr;   // 1474560
    const float* Bp = nullptr;   // 11520
    for (int i = 0; i < n_in; ++i) {
        const int s = in_sizes[i];
        if (s == BN * NN * DP)            u  = (const float*)d_in[i];
        else if (s == ND * NN * DD * DP)  W  = (const float*)d_in[i];
        else if (s == ND * NN)            Bp = (const float*)d_in[i];
    }
    float* out = (float*)d_out;
    unsigned* cnt = (unsigned*)d_ws;              // 4 counters (16 B)
    float* Tp = (float*)d_ws + 4;                 // 576*2560 fp32
    float* T  = Tp + (size_t)NBLK * CELLS;        // 2560 fp32
    float* Sp = T + CELLS;                        // 576*2560 fp32

    hipMemsetAsync(d_ws, 0, 4 * sizeof(unsigned), stream);  // zero barriers
    caps_fused<<<dim3(NBLK), 256, 0, stream>>>(u, W, Bp, Tp, T, Sp, out, cnt);
}